// Round 13
// baseline (3081.113 us; speedup 1.0000x reference)
//
#include <hip/hip_runtime.h>
#include <hip/hip_bf16.h>

#define F 128
#define RB 196            // rows per bucket
#define NB_MAX 511        // max buckets (nrows <= 100156)
#define BIN_CAP 16        // LDS records per bin (circular)
#define NBLK_BIN 512      // bin grid (2 blocks/CU)
#define NXS 16            // cursor/arena sub-segments (atomic de-contention)
#define NCG 16            // column groups (c >> 13) for gather locality
#define KEYS (RB * NCG)   // 3136 sort keys per bucket
#define NPH 8             // agg phases (2 colgroups = 4MB window each)
#define AGG_BLOCKS 2048   // persistent agg grid (full residency)

typedef __attribute__((ext_vector_type(8))) short bf16x8;
typedef __attribute__((ext_vector_type(4))) float f32x4;
typedef __attribute__((ext_vector_type(2))) float f32x2;
typedef __attribute__((ext_vector_type(2))) int   i32x2;

static __device__ __forceinline__ unsigned short f2bfbits(float f) {
    __hip_bfloat16 h = __float2bfloat16(f);
    return __builtin_bit_cast(unsigned short, h);
}
static __device__ __forceinline__ short f2bf(float f) {
    __hip_bfloat16 h = __float2bfloat16(f);
    return __builtin_bit_cast(short, h);
}

// ---------------------------------------------------------------------------
// MFMA GEMM (proven, standalone): wx = X @ W.T + b, 128x128 tile, K=128.
// Main path writes only bf16 wxh; fallback also writes f32 wxf.
// ---------------------------------------------------------------------------
__global__ __launch_bounds__(256) void gemm_mfma_kernel(
    const float* __restrict__ X, const float* __restrict__ W,
    const float* __restrict__ bias, float* __restrict__ wxf,
    __hip_bfloat16* __restrict__ wxh, int nrows, int writeF)
{
    __shared__ short xs[128][136];
    __shared__ short wt[128][136];
    __shared__ float bsh[128];

    int t = threadIdx.x;
    long row0 = (long)blockIdx.x * 128;

    {
        int r = t >> 1, h = t & 1;
        const float4* src = reinterpret_cast<const float4*>(W + r * F + h * 64);
#pragma unroll
        for (int i = 0; i < 16; ++i) {
            float4 v = src[i];
            short4 s;
            s.x = f2bf(v.x); s.y = f2bf(v.y); s.z = f2bf(v.z); s.w = f2bf(v.w);
            *reinterpret_cast<short4*>(&wt[r][h * 64 + i * 4]) = s;
        }
        if (t < 128) bsh[t] = bias[t];
    }
    {
        int r = t >> 1, h = t & 1;
        long gr = row0 + r; if (gr > nrows - 1) gr = nrows - 1;
        const float4* src = reinterpret_cast<const float4*>(X + gr * F + h * 64);
#pragma unroll
        for (int i = 0; i < 16; ++i) {
            float4 v = src[i];
            short4 s;
            s.x = f2bf(v.x); s.y = f2bf(v.y); s.z = f2bf(v.z); s.w = f2bf(v.w);
            *reinterpret_cast<short4*>(&xs[r][h * 64 + i * 4]) = s;
        }
    }
    __syncthreads();

    int wave = t >> 6, lane = t & 63;
    int l15 = lane & 15, lg = lane >> 4;
    int mrow = wave * 32;

    float bj[8];
#pragma unroll
    for (int nf = 0; nf < 8; ++nf) bj[nf] = bsh[nf * 16 + l15];

    f32x4 acc[2][8] = {};
#pragma unroll
    for (int ks = 0; ks < 4; ++ks) {
        bf16x8 a0 = *reinterpret_cast<const bf16x8*>(&xs[mrow + l15][ks * 32 + lg * 8]);
        bf16x8 a1 = *reinterpret_cast<const bf16x8*>(&xs[mrow + 16 + l15][ks * 32 + lg * 8]);
#pragma unroll
        for (int nf = 0; nf < 8; ++nf) {
            bf16x8 bfr = *reinterpret_cast<const bf16x8*>(&wt[nf * 16 + l15][ks * 32 + lg * 8]);
            acc[0][nf] = __builtin_amdgcn_mfma_f32_16x16x32_bf16(a0, bfr, acc[0][nf], 0, 0, 0);
            acc[1][nf] = __builtin_amdgcn_mfma_f32_16x16x32_bf16(a1, bfr, acc[1][nf], 0, 0, 0);
        }
    }

#pragma unroll
    for (int mf = 0; mf < 2; ++mf) {
#pragma unroll
        for (int i = 0; i < 4; ++i) {
            long grow = row0 + mrow + mf * 16 + lg * 4 + i;
            if (grow < nrows) {
#pragma unroll
                for (int nf = 0; nf < 8; ++nf) {
                    float v = acc[mf][nf][i] + bj[nf];
                    int col = nf * 16 + l15;
                    wxh[grow * F + col] = __float2bfloat16(v);
                    if (writeF) wxf[grow * F + col] = v;
                }
            }
        }
    }
}

// ---------------------------------------------------------------------------
// Counting-bin (proven, standalone): LDS write-combining + 16-way split
// cursors/arenas + prefetch. arena1 record = (rl<<17 | c, v^2 f32).
// ---------------------------------------------------------------------------
__global__ __launch_bounds__(256) void bin_edges_kernel(
    const int* __restrict__ rowi, const int* __restrict__ coli,
    const float* __restrict__ ev, int* __restrict__ cur2,
    int2* __restrict__ arena1, int E, int NB, int CAPX)
{
    __shared__ int2 bins[NB_MAX][BIN_CAP];
    __shared__ int  cnt[NB_MAX];
    __shared__ int  flushed[NB_MAX];

    int t = threadIdx.x;
    int x = blockIdx.x & (NXS - 1);
    for (int i = t; i < NB; i += 256) { cnt[i] = 0; flushed[i] = 0; }
    __syncthreads();

    long per   = ((long)E + NBLK_BIN - 1) / NBLK_BIN;
    long start = (long)blockIdx.x * per;
    long endE  = start + per; if (endE > E) endE = E;

    int r = 0, c = 0; float v = 0.f;
    {
        long i0 = start + t;
        if (i0 < endE) { r = rowi[i0]; c = coli[i0]; v = ev[i0]; }
    }

    for (long base = start; base < endE; base += 256) {
        if (base + t < endE) {
            float v2 = (r != c) ? v * v : 0.0f;
            int b  = r / RB;
            int rl = r - b * RB;
            int pos = atomicAdd(&cnt[b], 1);
            bins[b][pos & (BIN_CAP - 1)] = make_int2((rl << 17) | c, __float_as_int(v2));
        }
        int rn = 0, cn = 0; float vn = 0.f;
        {
            long i2 = base + 256 + t;
            if (i2 < endE) { rn = rowi[i2]; cn = coli[i2]; vn = ev[i2]; }
        }
        __syncthreads();
        for (int bb = t; bb < NB; bb += 256) {
            while (cnt[bb] - flushed[bb] >= 8) {
                int gpos = atomicAdd(&cur2[x * NB + bb], 8);
                if (gpos + 8 <= CAPX) {
                    const int2* src = &bins[bb][flushed[bb] & (BIN_CAP - 1)];
                    int2* dst = &arena1[((size_t)x * NB + bb) * CAPX + gpos];
                    const int4* s4 = (const int4*)src;
                    int4* d4 = (int4*)dst;
                    d4[0] = s4[0]; d4[1] = s4[1]; d4[2] = s4[2]; d4[3] = s4[3];
                }
                flushed[bb] += 8;
            }
        }
        __syncthreads();
        r = rn; c = cn; v = vn;
    }
    for (int bb = t; bb < NB; bb += 256) {
        int rem = cnt[bb] - flushed[bb];
        if (rem > 0) {
            int gpos = atomicAdd(&cur2[x * NB + bb], rem);
            if (gpos + rem <= CAPX) {
                int2* dst = &arena1[((size_t)x * NB + bb) * CAPX + gpos];
                for (int k = 0; k < rem; ++k)
                    dst[k] = bins[bb][(flushed[bb] + k) & (BIN_CAP - 1)];
            }
        }
    }
}

// ---------------------------------------------------------------------------
// Bucket-local counting sort (proven) + NEW: per-row colgroup offsets rowcg
// (16 ints/row, taken from koff post-scan) for the phase-aligned agg.
// arena2 record packed 4B: (bf16bits(v^2) << 17) | c.
// ---------------------------------------------------------------------------
__global__ __launch_bounds__(256) void sort_bucket_kernel(
    const int* __restrict__ cur2, const int2* __restrict__ arena1,
    unsigned int* __restrict__ arena2, int2* __restrict__ rowoff,
    int* __restrict__ rowcg,
    int nrows, int NB, int CAPX, int CAP)
{
    __shared__ int koff[KEYS];
    __shared__ int sscan[256];

    int b = blockIdx.x;
    int t = threadIdx.x;
    unsigned int* dst = arena2 + (size_t)b * CAP;

    for (int i = t; i < KEYS; i += 256) koff[i] = 0;
    __syncthreads();

    for (int x = 0; x < NXS; ++x) {
        int n_x = cur2[x * NB + b]; if (n_x > CAPX) n_x = CAPX;
        const int2* seg = arena1 + ((size_t)x * NB + b) * CAPX;
        for (int i = t; i < n_x; i += 256) {
            i32x2 rv = __builtin_nontemporal_load(reinterpret_cast<const i32x2*>(seg + i));
            int rx = rv[0];
            int key = (rx >> 17) * NCG + ((rx & 0x1FFFF) >> 13);
            atomicAdd(&koff[key], 1);
        }
    }
    __syncthreads();

    const int PER = (KEYS + 255) / 256;
    int lo = t * PER, hi = lo + PER; if (hi > KEYS) hi = KEYS; if (lo > KEYS) lo = KEYS;
    int s = 0;
    for (int i = lo; i < hi; ++i) s += koff[i];
    sscan[t] = s;
    __syncthreads();
#pragma unroll
    for (int d = 1; d < 256; d <<= 1) {
        int u = (t >= d) ? sscan[t - d] : 0;
        __syncthreads();
        sscan[t] += u;
        __syncthreads();
    }
    int total = sscan[255];
    int run = (t == 0) ? 0 : sscan[t - 1];
    for (int i = lo; i < hi; ++i) {
        int c0 = koff[i];
        koff[i] = run;
        run += c0;
    }
    __syncthreads();

    if (t < RB) {
        int grow = b * RB + t;
        if (grow < nrows) {
            int start = koff[t * NCG];
            int end   = (t == RB - 1) ? total : koff[(t + 1) * NCG];
            rowoff[grow] = make_int2(b * CAP + start, b * CAP + end);
#pragma unroll
            for (int g = 0; g < NCG; ++g)
                rowcg[(size_t)grow * NCG + g] = b * CAP + koff[t * NCG + g];
        }
    }
    __syncthreads();

    for (int x = 0; x < NXS; ++x) {
        int n_x = cur2[x * NB + b]; if (n_x > CAPX) n_x = CAPX;
        const int2* seg = arena1 + ((size_t)x * NB + b) * CAPX;
        for (int i = t; i < n_x; i += 256) {
            i32x2 rv = __builtin_nontemporal_load(reinterpret_cast<const i32x2*>(seg + i));
            int c = rv[0] & 0x1FFFF;
            int key = (rv[0] >> 17) * NCG + (c >> 13);
            int pos = atomicAdd(&koff[key], 1);
            unsigned int pk = ((unsigned int)f2bfbits(__int_as_float(rv[1])) << 17)
                              | (unsigned int)c;
            if (pos < CAP) dst[pos] = pk;
        }
    }
}

// ---------------------------------------------------------------------------
// Phase-aligned persistent agg: 8192 waves, each owns rows wv + k*8192.
// Outer loop over 8 column phases (2 colgroups = 4MB window ~ L2); all
// waves sweep the same window concurrently -> capacity misses drop.
// acc[16][2] statically unrolled (rule: no runtime indexing).
// ---------------------------------------------------------------------------
__global__ __launch_bounds__(256) void agg_row_kernel(
    const int2* __restrict__ rowoff, const int* __restrict__ rowcg,
    const unsigned int* __restrict__ arena2,
    const unsigned int* __restrict__ wxh32, float* __restrict__ out,
    int nrows)
{
    int wv   = (blockIdx.x * 256 + threadIdx.x) >> 6;
    int lane = threadIdx.x & 63;
    const int totw = AGG_BLOCKS * 4;
    const unsigned int* wl = wxh32 + lane;

    float acc[16][2];
#pragma unroll
    for (int k = 0; k < 16; ++k) { acc[k][0] = 0.f; acc[k][1] = 0.f; }

    for (int ph = 0; ph < NPH; ++ph) {
        int g0 = ph * (NCG / NPH);
        int g1 = g0 + (NCG / NPH);
#pragma unroll
        for (int k = 0; k < 16; ++k) {
            int r = wv + k * totw;
            if (r >= nrows) break;
            int e  = __builtin_amdgcn_readfirstlane(rowcg[(size_t)r * NCG + g0]);
            int e1 = (g1 < NCG)
                   ? __builtin_amdgcn_readfirstlane(rowcg[(size_t)r * NCG + g1])
                   : __builtin_amdgcn_readfirstlane(rowoff[r].y);
            for (; e + 1 < e1; e += 2) {
                unsigned int p0 = __builtin_nontemporal_load(arena2 + e);
                unsigned int p1 = __builtin_nontemporal_load(arena2 + e + 1);
                unsigned int g0v = wl[(size_t)(p0 & 0x1FFFF) * 64];
                unsigned int g1v = wl[(size_t)(p1 & 0x1FFFF) * 64];
                float v0 = __uint_as_float((p0 >> 17) << 16);
                float v1 = __uint_as_float((p1 >> 17) << 16);
                acc[k][0] = fmaf(v0, __uint_as_float(g0v << 16), acc[k][0]);
                acc[k][1] = fmaf(v0, __uint_as_float(g0v & 0xFFFF0000u), acc[k][1]);
                acc[k][0] = fmaf(v1, __uint_as_float(g1v << 16), acc[k][0]);
                acc[k][1] = fmaf(v1, __uint_as_float(g1v & 0xFFFF0000u), acc[k][1]);
            }
            if (e < e1) {
                unsigned int p0 = __builtin_nontemporal_load(arena2 + e);
                unsigned int g0v = wl[(size_t)(p0 & 0x1FFFF) * 64];
                float v0 = __uint_as_float((p0 >> 17) << 16);
                acc[k][0] = fmaf(v0, __uint_as_float(g0v << 16), acc[k][0]);
                acc[k][1] = fmaf(v0, __uint_as_float(g0v & 0xFFFF0000u), acc[k][1]);
            }
        }
    }

#pragma unroll
    for (int k = 0; k < 16; ++k) {
        int r = wv + k * totw;
        if (r >= nrows) break;
        unsigned int gw = wl[(size_t)r * 64];
        f32x2 o;
        o[0] = __uint_as_float(gw << 16) * acc[k][0];
        o[1] = __uint_as_float(gw & 0xFFFF0000u) * acc[k][1];
        __builtin_nontemporal_store(o, reinterpret_cast<f32x2*>(out + (size_t)r * F + lane * 2));
    }
}

// ---------------------------------------------------------------------------
// Last-resort fallback (round-1, proven): atomic scatter + finalize
// ---------------------------------------------------------------------------
__global__ __launch_bounds__(256) void edge_scatter_kernel(
    const int* __restrict__ rowi, const int* __restrict__ coli,
    const float* __restrict__ ev, const float* __restrict__ wx,
    float* __restrict__ temp, int E)
{
    int tid = blockIdx.x * 256 + threadIdx.x;
    int e   = tid >> 5;
    if (e >= E) return;
    int lane = tid & 31;
    int r = rowi[e];
    int c = coli[e];
    if (r == c) return;
    float v = ev[e];
    v = v * v;
    const float4 wv = *reinterpret_cast<const float4*>(wx + (size_t)c * F + lane * 4);
    float* tp = temp + (size_t)r * F + lane * 4;
    atomicAdd(tp + 0, v * wv.x);
    atomicAdd(tp + 1, v * wv.y);
    atomicAdd(tp + 2, v * wv.z);
    atomicAdd(tp + 3, v * wv.w);
}

__global__ __launch_bounds__(256) void finalize_kernel(
    float* __restrict__ out, const float* __restrict__ temp, int n4)
{
    int i = blockIdx.x * 256 + threadIdx.x;
    if (i >= n4) return;
    float4 o  = reinterpret_cast<float4*>(out)[i];
    float4 tv = reinterpret_cast<const float4*>(temp)[i];
    o.x *= tv.x; o.y *= tv.y; o.z *= tv.z; o.w *= tv.w;
    reinterpret_cast<float4*>(out)[i] = o;
}

__global__ void Interaction_GraphConvolution_55963423867450_kernel() {}

extern "C" void kernel_launch(void* const* d_in, const int* in_sizes, int n_in,
                              void* d_out, int out_size, void* d_ws, size_t ws_size,
                              hipStream_t stream)
{
    const float* X  = (const float*)d_in[0];
    const int*   ei = (const int*)d_in[1];   // [2, E] int32
    const float* ev = (const float*)d_in[2];
    const float* W  = (const float*)d_in[3];
    const float* b  = (const float*)d_in[4];
    float* out = (float*)d_out;

    int nrows = in_sizes[0] / F;
    int E     = in_sizes[2];
    const int* rowi = ei;
    const int* coli = ei + E;

    int ntiles = (nrows + 127) / 128;

    int NB = (nrows + RB - 1) / RB;
    if (NB <= NB_MAX && nrows < (1 << 17)) {
        long avg = (long)E / NB;                                 // records per bucket
        int CAP  = (int)(((avg * 9) / 8 + 192 + 7) & ~7L);       // arena2 per-bucket
        int CAPX = (int)(((avg / NXS) * 5 / 4 + 64 + 7) & ~7L);  // per (x,bucket) segment

        char* p = (char*)d_ws;
        __hip_bfloat16* wxh = (__hip_bfloat16*)p;
        p += (size_t)nrows * F * sizeof(__hip_bfloat16);
        int* cur2 = (int*)p;
        p += (size_t)NXS * NB * sizeof(int);
        p = (char*)(((uintptr_t)p + 63) & ~(uintptr_t)63);
        int2* rowoff = (int2*)p;
        p += (size_t)nrows * sizeof(int2);
        int* rowcg = (int*)p;
        p += (size_t)nrows * NCG * sizeof(int);
        int2* arena1 = (int2*)p;
        p += (size_t)NXS * NB * CAPX * sizeof(int2);
        unsigned int* arena2 = (unsigned int*)p;
        p += (size_t)NB * CAP * sizeof(unsigned int);
        size_t need = (size_t)(p - (char*)d_ws);

        if (ws_size >= need) {
            hipMemsetAsync(cur2, 0, (size_t)NXS * NB * sizeof(int), stream);
            gemm_mfma_kernel<<<ntiles, 256, 0, stream>>>(X, W, b, nullptr, wxh, nrows, 0);
            bin_edges_kernel<<<NBLK_BIN, 256, 0, stream>>>(rowi, coli, ev, cur2,
                                                           arena1, E, NB, CAPX);
            sort_bucket_kernel<<<NB, 256, 0, stream>>>(cur2, arena1, arena2,
                                                       rowoff, rowcg,
                                                       nrows, NB, CAPX, CAP);
            agg_row_kernel<<<AGG_BLOCKS, 256, 0, stream>>>(rowoff, rowcg, arena2,
                                                           (const unsigned int*)wxh,
                                                           out, nrows);
            return;
        }
    }

    // ---------- last resort: atomic scatter (round-1) ----------
    float* temp = (float*)d_ws;   // [nrows, 128]
    hipMemsetAsync(temp, 0, (size_t)nrows * F * sizeof(float), stream);
    __hip_bfloat16* wxh_dummy = (__hip_bfloat16*)((char*)d_ws + (size_t)nrows * F * sizeof(float));
    gemm_mfma_kernel<<<ntiles, 256, 0, stream>>>(X, W, b, out, wxh_dummy, nrows, 1);
    long ethreads = (long)E * 32;
    int  eblocks32 = (int)((ethreads + 255) / 256);
    edge_scatter_kernel<<<eblocks32, 256, 0, stream>>>(rowi, coli, ev, out, temp, E);
    int n4 = nrows * F / 4;
    finalize_kernel<<<(n4 + 255) / 256, 256, 0, stream>>>(out, temp, n4);
}

// Round 14
// 222.211 us; speedup vs baseline: 13.8657x; 13.8657x over previous
//
#include <hip/hip_runtime.h>
#include <hip/hip_bf16.h>

#define F 128
#define RB 196            // rows per bucket
#define NB_MAX 511        // max buckets (nrows <= 100156)
#define BIN_CAP 16        // LDS records per bin (circular)
#define NBLK_BIN 512      // bin grid (2 blocks/CU)
#define NXS 16            // cursor/arena sub-segments (atomic de-contention)
#define NCG 16            // column groups (c >> 13) for gather locality
#define KEYS (RB * NCG)   // 3136 sort keys per bucket

typedef __attribute__((ext_vector_type(8))) short bf16x8;
typedef __attribute__((ext_vector_type(4))) float f32x4;
typedef __attribute__((ext_vector_type(2))) float f32x2;
typedef __attribute__((ext_vector_type(2))) int   i32x2;

static __device__ __forceinline__ unsigned short f2bfbits(float f) {
    __hip_bfloat16 h = __float2bfloat16(f);
    return __builtin_bit_cast(unsigned short, h);
}
static __device__ __forceinline__ short f2bf(float f) {
    __hip_bfloat16 h = __float2bfloat16(f);
    return __builtin_bit_cast(short, h);
}

// ---------------------------------------------------------------------------
// MFMA GEMM (proven): wx = X @ W.T + b, 128x128 tile, K=128.
// Main path writes only bf16 wxh; fallback also writes f32 wxf.
// ---------------------------------------------------------------------------
__global__ __launch_bounds__(256) void gemm_mfma_kernel(
    const float* __restrict__ X, const float* __restrict__ W,
    const float* __restrict__ bias, float* __restrict__ wxf,
    __hip_bfloat16* __restrict__ wxh, int nrows, int writeF)
{
    __shared__ short xs[128][136];
    __shared__ short wt[128][136];
    __shared__ float bsh[128];

    int t = threadIdx.x;
    long row0 = (long)blockIdx.x * 128;

    {
        int r = t >> 1, h = t & 1;
        const float4* src = reinterpret_cast<const float4*>(W + r * F + h * 64);
#pragma unroll
        for (int i = 0; i < 16; ++i) {
            float4 v = src[i];
            short4 s;
            s.x = f2bf(v.x); s.y = f2bf(v.y); s.z = f2bf(v.z); s.w = f2bf(v.w);
            *reinterpret_cast<short4*>(&wt[r][h * 64 + i * 4]) = s;
        }
        if (t < 128) bsh[t] = bias[t];
    }
    {
        int r = t >> 1, h = t & 1;
        long gr = row0 + r; if (gr > nrows - 1) gr = nrows - 1;
        const float4* src = reinterpret_cast<const float4*>(X + gr * F + h * 64);
#pragma unroll
        for (int i = 0; i < 16; ++i) {
            float4 v = src[i];
            short4 s;
            s.x = f2bf(v.x); s.y = f2bf(v.y); s.z = f2bf(v.z); s.w = f2bf(v.w);
            *reinterpret_cast<short4*>(&xs[r][h * 64 + i * 4]) = s;
        }
    }
    __syncthreads();

    int wave = t >> 6, lane = t & 63;
    int l15 = lane & 15, lg = lane >> 4;
    int mrow = wave * 32;

    float bj[8];
#pragma unroll
    for (int nf = 0; nf < 8; ++nf) bj[nf] = bsh[nf * 16 + l15];

    f32x4 acc[2][8] = {};
#pragma unroll
    for (int ks = 0; ks < 4; ++ks) {
        bf16x8 a0 = *reinterpret_cast<const bf16x8*>(&xs[mrow + l15][ks * 32 + lg * 8]);
        bf16x8 a1 = *reinterpret_cast<const bf16x8*>(&xs[mrow + 16 + l15][ks * 32 + lg * 8]);
#pragma unroll
        for (int nf = 0; nf < 8; ++nf) {
            bf16x8 bfr = *reinterpret_cast<const bf16x8*>(&wt[nf * 16 + l15][ks * 32 + lg * 8]);
            acc[0][nf] = __builtin_amdgcn_mfma_f32_16x16x32_bf16(a0, bfr, acc[0][nf], 0, 0, 0);
            acc[1][nf] = __builtin_amdgcn_mfma_f32_16x16x32_bf16(a1, bfr, acc[1][nf], 0, 0, 0);
        }
    }

#pragma unroll
    for (int mf = 0; mf < 2; ++mf) {
#pragma unroll
        for (int i = 0; i < 4; ++i) {
            long grow = row0 + mrow + mf * 16 + lg * 4 + i;
            if (grow < nrows) {
#pragma unroll
                for (int nf = 0; nf < 8; ++nf) {
                    float v = acc[mf][nf][i] + bj[nf];
                    int col = nf * 16 + l15;
                    wxh[grow * F + col] = __float2bfloat16(v);
                    if (writeF) wxf[grow * F + col] = v;
                }
            }
        }
    }
}

// ---------------------------------------------------------------------------
// Counting-bin (proven): LDS write-combining + 16-way split cursors/arenas
// + prefetch. arena1 record = (rl<<17 | c, v^2 f32); diagonal v^2 = 0.
// ---------------------------------------------------------------------------
__global__ __launch_bounds__(256) void bin_edges_kernel(
    const int* __restrict__ rowi, const int* __restrict__ coli,
    const float* __restrict__ ev, int* __restrict__ cur2,
    int2* __restrict__ arena1, int E, int NB, int CAPX)
{
    __shared__ int2 bins[NB_MAX][BIN_CAP];
    __shared__ int  cnt[NB_MAX];
    __shared__ int  flushed[NB_MAX];

    int t = threadIdx.x;
    int x = blockIdx.x & (NXS - 1);
    for (int i = t; i < NB; i += 256) { cnt[i] = 0; flushed[i] = 0; }
    __syncthreads();

    long per   = ((long)E + NBLK_BIN - 1) / NBLK_BIN;
    long start = (long)blockIdx.x * per;
    long endE  = start + per; if (endE > E) endE = E;

    int r = 0, c = 0; float v = 0.f;
    {
        long i0 = start + t;
        if (i0 < endE) { r = rowi[i0]; c = coli[i0]; v = ev[i0]; }
    }

    for (long base = start; base < endE; base += 256) {
        if (base + t < endE) {
            float v2 = (r != c) ? v * v : 0.0f;
            int b  = r / RB;
            int rl = r - b * RB;
            int pos = atomicAdd(&cnt[b], 1);
            bins[b][pos & (BIN_CAP - 1)] = make_int2((rl << 17) | c, __float_as_int(v2));
        }
        int rn = 0, cn = 0; float vn = 0.f;
        {
            long i2 = base + 256 + t;
            if (i2 < endE) { rn = rowi[i2]; cn = coli[i2]; vn = ev[i2]; }
        }
        __syncthreads();
        for (int bb = t; bb < NB; bb += 256) {
            while (cnt[bb] - flushed[bb] >= 8) {
                int gpos = atomicAdd(&cur2[x * NB + bb], 8);
                if (gpos + 8 <= CAPX) {
                    const int2* src = &bins[bb][flushed[bb] & (BIN_CAP - 1)];
                    int2* dst = &arena1[((size_t)x * NB + bb) * CAPX + gpos];
                    const int4* s4 = (const int4*)src;
                    int4* d4 = (int4*)dst;
                    d4[0] = s4[0]; d4[1] = s4[1]; d4[2] = s4[2]; d4[3] = s4[3];
                }
                flushed[bb] += 8;
            }
        }
        __syncthreads();
        r = rn; c = cn; v = vn;
    }
    for (int bb = t; bb < NB; bb += 256) {
        int rem = cnt[bb] - flushed[bb];
        if (rem > 0) {
            int gpos = atomicAdd(&cur2[x * NB + bb], rem);
            if (gpos + rem <= CAPX) {
                int2* dst = &arena1[((size_t)x * NB + bb) * CAPX + gpos];
                for (int k = 0; k < rem; ++k)
                    dst[k] = bins[bb][(flushed[bb] + k) & (BIN_CAP - 1)];
            }
        }
    }
}

// ---------------------------------------------------------------------------
// Bucket-local counting sort (proven): key = rl*NCG + (c>>13); arena2 record
// packed 4B: (bf16bits(v^2) << 17) | c. rowoff = (start,end) into arena2.
// arena1 reads non-temporal (read-once stream).
// ---------------------------------------------------------------------------
__global__ __launch_bounds__(256) void sort_bucket_kernel(
    const int* __restrict__ cur2, const int2* __restrict__ arena1,
    unsigned int* __restrict__ arena2, int2* __restrict__ rowoff,
    int nrows, int NB, int CAPX, int CAP)
{
    __shared__ int koff[KEYS];
    __shared__ int sscan[256];

    int b = blockIdx.x;
    int t = threadIdx.x;
    unsigned int* dst = arena2 + (size_t)b * CAP;

    for (int i = t; i < KEYS; i += 256) koff[i] = 0;
    __syncthreads();

    for (int x = 0; x < NXS; ++x) {
        int n_x = cur2[x * NB + b]; if (n_x > CAPX) n_x = CAPX;
        const int2* seg = arena1 + ((size_t)x * NB + b) * CAPX;
        for (int i = t; i < n_x; i += 256) {
            i32x2 rv = __builtin_nontemporal_load(reinterpret_cast<const i32x2*>(seg + i));
            int rx = rv[0];
            int key = (rx >> 17) * NCG + ((rx & 0x1FFFF) >> 13);
            atomicAdd(&koff[key], 1);
        }
    }
    __syncthreads();

    const int PER = (KEYS + 255) / 256;
    int lo = t * PER, hi = lo + PER; if (hi > KEYS) hi = KEYS; if (lo > KEYS) lo = KEYS;
    int s = 0;
    for (int i = lo; i < hi; ++i) s += koff[i];
    sscan[t] = s;
    __syncthreads();
#pragma unroll
    for (int d = 1; d < 256; d <<= 1) {
        int u = (t >= d) ? sscan[t - d] : 0;
        __syncthreads();
        sscan[t] += u;
        __syncthreads();
    }
    int total = sscan[255];
    int run = (t == 0) ? 0 : sscan[t - 1];
    for (int i = lo; i < hi; ++i) {
        int c0 = koff[i];
        koff[i] = run;
        run += c0;
    }
    __syncthreads();

    if (t < RB) {
        int grow = b * RB + t;
        if (grow < nrows) {
            int start = koff[t * NCG];
            int end   = (t == RB - 1) ? total : koff[(t + 1) * NCG];
            rowoff[grow] = make_int2(b * CAP + start, b * CAP + end);
        }
    }
    __syncthreads();

    for (int x = 0; x < NXS; ++x) {
        int n_x = cur2[x * NB + b]; if (n_x > CAPX) n_x = CAPX;
        const int2* seg = arena1 + ((size_t)x * NB + b) * CAPX;
        for (int i = t; i < n_x; i += 256) {
            i32x2 rv = __builtin_nontemporal_load(reinterpret_cast<const i32x2*>(seg + i));
            int c = rv[0] & 0x1FFFF;
            int key = (rv[0] >> 17) * NCG + (c >> 13);
            int pos = atomicAdd(&koff[key], 1);
            unsigned int pk = ((unsigned int)f2bfbits(__int_as_float(rv[1])) << 17)
                              | (unsigned int)c;
            if (pos < CAP) dst[pos] = pk;
        }
    }
}

// ---------------------------------------------------------------------------
// One wave per row (proven best, 106 us in round-12 run): 8-deep unroll,
// NT loads on arena2 (read-once), NT store on out (write-once full lines).
// Final multiply from the row's own bf16 wx.
// ---------------------------------------------------------------------------
__global__ __launch_bounds__(256) void agg_row_kernel(
    const int2* __restrict__ rowoff, const unsigned int* __restrict__ arena2,
    const unsigned int* __restrict__ wxh32, float* __restrict__ out,
    int nrows)
{
    int wid  = (blockIdx.x * 256 + threadIdx.x) >> 6;
    int lane = threadIdx.x & 63;
    if (wid >= nrows) return;

    int2 se   = rowoff[wid];
    int start = __builtin_amdgcn_readfirstlane(se.x);
    int end   = __builtin_amdgcn_readfirstlane(se.y);

    unsigned int gw = wxh32[(size_t)wid * 64 + lane];   // self row, hoisted
    const unsigned int* wl = wxh32 + lane;

    float accx = 0.f, accy = 0.f;
    int e = start;
    for (; e + 7 < end; e += 8) {
        unsigned int p0 = __builtin_nontemporal_load(arena2 + e);
        unsigned int p1 = __builtin_nontemporal_load(arena2 + e + 1);
        unsigned int p2 = __builtin_nontemporal_load(arena2 + e + 2);
        unsigned int p3 = __builtin_nontemporal_load(arena2 + e + 3);
        unsigned int p4 = __builtin_nontemporal_load(arena2 + e + 4);
        unsigned int p5 = __builtin_nontemporal_load(arena2 + e + 5);
        unsigned int p6 = __builtin_nontemporal_load(arena2 + e + 6);
        unsigned int p7 = __builtin_nontemporal_load(arena2 + e + 7);
        unsigned int g0 = wl[(size_t)(p0 & 0x1FFFF) * 64];
        unsigned int g1 = wl[(size_t)(p1 & 0x1FFFF) * 64];
        unsigned int g2 = wl[(size_t)(p2 & 0x1FFFF) * 64];
        unsigned int g3 = wl[(size_t)(p3 & 0x1FFFF) * 64];
        unsigned int g4 = wl[(size_t)(p4 & 0x1FFFF) * 64];
        unsigned int g5 = wl[(size_t)(p5 & 0x1FFFF) * 64];
        unsigned int g6 = wl[(size_t)(p6 & 0x1FFFF) * 64];
        unsigned int g7 = wl[(size_t)(p7 & 0x1FFFF) * 64];
        float v0 = __uint_as_float((p0 >> 17) << 16);
        float v1 = __uint_as_float((p1 >> 17) << 16);
        float v2 = __uint_as_float((p2 >> 17) << 16);
        float v3 = __uint_as_float((p3 >> 17) << 16);
        float v4 = __uint_as_float((p4 >> 17) << 16);
        float v5 = __uint_as_float((p5 >> 17) << 16);
        float v6 = __uint_as_float((p6 >> 17) << 16);
        float v7 = __uint_as_float((p7 >> 17) << 16);
        accx = fmaf(v0, __uint_as_float(g0 << 16), accx);
        accy = fmaf(v0, __uint_as_float(g0 & 0xFFFF0000u), accy);
        accx = fmaf(v1, __uint_as_float(g1 << 16), accx);
        accy = fmaf(v1, __uint_as_float(g1 & 0xFFFF0000u), accy);
        accx = fmaf(v2, __uint_as_float(g2 << 16), accx);
        accy = fmaf(v2, __uint_as_float(g2 & 0xFFFF0000u), accy);
        accx = fmaf(v3, __uint_as_float(g3 << 16), accx);
        accy = fmaf(v3, __uint_as_float(g3 & 0xFFFF0000u), accy);
        accx = fmaf(v4, __uint_as_float(g4 << 16), accx);
        accy = fmaf(v4, __uint_as_float(g4 & 0xFFFF0000u), accy);
        accx = fmaf(v5, __uint_as_float(g5 << 16), accx);
        accy = fmaf(v5, __uint_as_float(g5 & 0xFFFF0000u), accy);
        accx = fmaf(v6, __uint_as_float(g6 << 16), accx);
        accy = fmaf(v6, __uint_as_float(g6 & 0xFFFF0000u), accy);
        accx = fmaf(v7, __uint_as_float(g7 << 16), accx);
        accy = fmaf(v7, __uint_as_float(g7 & 0xFFFF0000u), accy);
    }
    for (; e < end; ++e) {
        unsigned int p0 = __builtin_nontemporal_load(arena2 + e);
        unsigned int g0 = wl[(size_t)(p0 & 0x1FFFF) * 64];
        float v0 = __uint_as_float((p0 >> 17) << 16);
        accx = fmaf(v0, __uint_as_float(g0 << 16), accx);
        accy = fmaf(v0, __uint_as_float(g0 & 0xFFFF0000u), accy);
    }

    f32x2 o;
    o[0] = __uint_as_float(gw << 16) * accx;
    o[1] = __uint_as_float(gw & 0xFFFF0000u) * accy;
    __builtin_nontemporal_store(o, reinterpret_cast<f32x2*>(out + (size_t)wid * F + lane * 2));
}

// ---------------------------------------------------------------------------
// Last-resort fallback (round-1, proven): atomic scatter + finalize
// ---------------------------------------------------------------------------
__global__ __launch_bounds__(256) void edge_scatter_kernel(
    const int* __restrict__ rowi, const int* __restrict__ coli,
    const float* __restrict__ ev, const float* __restrict__ wx,
    float* __restrict__ temp, int E)
{
    int tid = blockIdx.x * 256 + threadIdx.x;
    int e   = tid >> 5;
    if (e >= E) return;
    int lane = tid & 31;
    int r = rowi[e];
    int c = coli[e];
    if (r == c) return;
    float v = ev[e];
    v = v * v;
    const float4 wv = *reinterpret_cast<const float4*>(wx + (size_t)c * F + lane * 4);
    float* tp = temp + (size_t)r * F + lane * 4;
    atomicAdd(tp + 0, v * wv.x);
    atomicAdd(tp + 1, v * wv.y);
    atomicAdd(tp + 2, v * wv.z);
    atomicAdd(tp + 3, v * wv.w);
}

__global__ __launch_bounds__(256) void finalize_kernel(
    float* __restrict__ out, const float* __restrict__ temp, int n4)
{
    int i = blockIdx.x * 256 + threadIdx.x;
    if (i >= n4) return;
    float4 o  = reinterpret_cast<float4*>(out)[i];
    float4 tv = reinterpret_cast<const float4*>(temp)[i];
    o.x *= tv.x; o.y *= tv.y; o.z *= tv.z; o.w *= tv.w;
    reinterpret_cast<float4*>(out)[i] = o;
}

__global__ void Interaction_GraphConvolution_55963423867450_kernel() {}

extern "C" void kernel_launch(void* const* d_in, const int* in_sizes, int n_in,
                              void* d_out, int out_size, void* d_ws, size_t ws_size,
                              hipStream_t stream)
{
    const float* X  = (const float*)d_in[0];
    const int*   ei = (const int*)d_in[1];   // [2, E] int32
    const float* ev = (const float*)d_in[2];
    const float* W  = (const float*)d_in[3];
    const float* b  = (const float*)d_in[4];
    float* out = (float*)d_out;

    int nrows = in_sizes[0] / F;
    int E     = in_sizes[2];
    const int* rowi = ei;
    const int* coli = ei + E;

    int ntiles = (nrows + 127) / 128;

    int NB = (nrows + RB - 1) / RB;
    if (NB <= NB_MAX && nrows < (1 << 17)) {
        long avg = (long)E / NB;                                 // records per bucket
        int CAP  = (int)(((avg * 9) / 8 + 192 + 7) & ~7L);       // arena2 per-bucket
        int CAPX = (int)(((avg / NXS) * 5 / 4 + 64 + 7) & ~7L);  // per (x,bucket) segment

        char* p = (char*)d_ws;
        __hip_bfloat16* wxh = (__hip_bfloat16*)p;
        p += (size_t)nrows * F * sizeof(__hip_bfloat16);
        int* cur2 = (int*)p;
        p += (size_t)NXS * NB * sizeof(int);
        p = (char*)(((uintptr_t)p + 63) & ~(uintptr_t)63);
        int2* rowoff = (int2*)p;
        p += (size_t)nrows * sizeof(int2);
        int2* arena1 = (int2*)p;
        p += (size_t)NXS * NB * CAPX * sizeof(int2);
        unsigned int* arena2 = (unsigned int*)p;
        p += (size_t)NB * CAP * sizeof(unsigned int);
        size_t need = (size_t)(p - (char*)d_ws);

        if (ws_size >= need) {
            hipMemsetAsync(cur2, 0, (size_t)NXS * NB * sizeof(int), stream);
            gemm_mfma_kernel<<<ntiles, 256, 0, stream>>>(X, W, b, nullptr, wxh, nrows, 0);
            bin_edges_kernel<<<NBLK_BIN, 256, 0, stream>>>(rowi, coli, ev, cur2,
                                                           arena1, E, NB, CAPX);
            sort_bucket_kernel<<<NB, 256, 0, stream>>>(cur2, arena1, arena2,
                                                       rowoff, nrows, NB, CAPX, CAP);
            int ablocks = (int)(((long)nrows * 64 + 255) / 256);
            agg_row_kernel<<<ablocks, 256, 0, stream>>>(rowoff, arena2,
                                                        (const unsigned int*)wxh,
                                                        out, nrows);
            return;
        }
    }

    // ---------- last resort: atomic scatter (round-1) ----------
    float* temp = (float*)d_ws;   // [nrows, 128]
    hipMemsetAsync(temp, 0, (size_t)nrows * F * sizeof(float), stream);
    __hip_bfloat16* wxh_dummy = (__hip_bfloat16*)((char*)d_ws + (size_t)nrows * F * sizeof(float));
    gemm_mfma_kernel<<<ntiles, 256, 0, stream>>>(X, W, b, out, wxh_dummy, nrows, 1);
    long ethreads = (long)E * 32;
    int  eblocks32 = (int)((ethreads + 255) / 256);
    edge_scatter_kernel<<<eblocks32, 256, 0, stream>>>(rowi, coli, ev, out, temp, E);
    int n4 = nrows * F / 4;
    finalize_kernel<<<(n4 + 255) / 256, 256, 0, stream>>>(out, temp, n4);
}